// Round 10
// baseline (73.148 us; speedup 1.0000x reference)
//
#include <hip/hip_runtime.h>
#include <stdint.h>

#define T_TOK 8192
#define DIMK 1024
#define NEXP 8
#define BM 128
#define BN 64
#define BK 64
#define NTK (DIMK / BK)               /* 16 K-steps */
#define MAXROWS (T_TOK + NEXP * BM)   /* 9216 gathered rows incl. padding */
#define MAXTILES (T_TOK / BM + NEXP)  /* 72 row tiles worst case */
#define NT (DIMK / BN)                /* 16 n tiles */
#define NWG (MAXTILES * NT)           /* 1152 blocks, 1152 % 8 == 0 */

typedef __attribute__((ext_vector_type(4))) float f32x4;
typedef __attribute__((ext_vector_type(8))) short short8;
typedef __attribute__((ext_vector_type(8))) unsigned short us8;

__device__ __forceinline__ unsigned short f2bf(float f) {
  uint32_t u = __builtin_bit_cast(uint32_t, f);
  u += 0x7FFFu + ((u >> 16) & 1u);   // RTNE
  return (unsigned short)(u >> 16);
}

__device__ __forceinline__ void gload_lds16(const void* g, void* l) {
  __builtin_amdgcn_global_load_lds(
      (const __attribute__((address_space(1))) void*)g,
      (__attribute__((address_space(3))) void*)l, 16, 0, 0);
}

// ---- fused: prep (block 0) || W fp32->bf16 (X is consumed fp32 by the GEMM)
__global__ void k_prep_conv(const int* __restrict__ idx, const float* __restrict__ W,
                            int* __restrict__ hdr, int* __restrict__ row2tok,
                            unsigned short* __restrict__ Wb) {
  const int tid = threadIdx.x;
  const int b = blockIdx.x;
  if (b == 0) {
    __shared__ int h[NEXP];
    __shared__ int cur[NEXP];
    __shared__ int segs[NEXP + 1];
    if (tid < NEXP) h[tid] = 0;
    __syncthreads();
    for (int i = tid; i < T_TOK; i += 256) atomicAdd(&h[idx[i]], 1);
    __syncthreads();
    if (tid == 0) {
      int off = 0;
      for (int e = 0; e < NEXP; e++) {
        segs[e] = off; cur[e] = off;
        hdr[e] = h[e]; hdr[8 + e] = off;
        off += ((h[e] + BM - 1) >> 7) << 7;
      }
      segs[NEXP] = off;
    }
    __syncthreads();
    for (int e = 0; e < NEXP; e++)
      for (int p = segs[e] + h[e] + tid; p < segs[e + 1]; p += 256) row2tok[p] = -1;
    for (int p = segs[NEXP] + tid; p < MAXROWS; p += 256) row2tok[p] = -1;
    for (int i = tid; i < T_TOK; i += 256) {
      int e = idx[i];
      int pos = atomicAdd(&cur[e], 1);
      row2tok[pos] = i;
    }
    return;
  }
  // W: 4096 blocks x 2048 elems
  size_t base = (size_t)(b - 1) * 2048 + tid * 8;
  const float* src = W + base;
  unsigned short* dst = Wb + base;
  f32x4 v0 = *(const f32x4*)src;
  f32x4 v1 = *(const f32x4*)(src + 4);
  us8 o;
  o[0] = f2bf(v0[0]); o[1] = f2bf(v0[1]); o[2] = f2bf(v0[2]); o[3] = f2bf(v0[3]);
  o[4] = f2bf(v1[0]); o[5] = f2bf(v1[1]); o[6] = f2bf(v1[2]); o[7] = f2bf(v1[3]);
  *(us8*)dst = o;
}

// ---- grouped GEMM, A reg-staged from fp32 X (fused gather + convert) -------
// R5/R7 single-buffer 2-barrier structure, 24 KB LDS (6 blocks/CU possible,
// grid needs 4.5 — one dispatch round). A: per-lane fp32 loads from X at
// pre-swizzled source columns -> f2bf (identical RTNE as prep) -> ds_write
// to the SAME linear LDS image as gload_lds produced. B: gload_lds from Wb.
__global__ __launch_bounds__(256, 4) void k_gemm(
    const float* __restrict__ X, const unsigned short* __restrict__ Wb,
    const int* __restrict__ hdr, const int* __restrict__ row2tok,
    float* __restrict__ out) {
  __shared__ unsigned short A_lds[BM * BK];  // 16 KB
  __shared__ unsigned short B_lds[BN * BK];  // 8 KB

  // XCD chunk remap: NWG=1152 % 8 == 0 -> wgid = xcd*144 + orig/8.
  const int orig = blockIdx.x;
  const int wgid = (orig & 7) * (NWG / 8) + (orig >> 3);
  int tile = wgid >> 4;               // row tile
  const int n0 = (wgid & 15) * BN;    // output column base

  // map row tile -> (expert, gathered row0) over padded segments
  int e = -1, row0 = 0;
  for (int i = 0; i < NEXP; i++) {
    int te = (hdr[i] + BM - 1) >> 7;
    if (e < 0) {
      if (tile < te) { e = i; row0 = hdr[8 + i] + tile * BM; }
      else tile -= te;
    }
  }
  if (e < 0) return;

  const int tid = threadIdx.x;
  const int lane = tid & 63;
  const int wid = tid >> 6;
  const int wr = wid >> 1, wc = wid & 1;   // wave tile 64x32

  // staging geometry: lane covers 16B at LDS linear (chunk*1024 + lane*16).
  // LDS row = chunk*8 + (lane>>3); read side XORs col by (row&7)<<4, so the
  // *source* column carries the same XOR (both-sides-or-neither).
  const int st_r = lane >> 3;
  const int swz_col8 = ((lane & 7) ^ st_r) * 8;      // fp32/bf16 elem col base
  const int st_cb = swz_col8 * 2;                    // byte col for bf16 B

  // resolve this lane's 4 A-row tokens ONCE (rows fixed across K-steps).
  // pad rows (tok=-1) clamp to row 0: garbage values, outputs never stored.
  const float* a_src[4];
#pragma unroll
  for (int j = 0; j < 4; j++) {
    int r = (wid * 4 + j) * 8 + st_r;
    int tok = row2tok[row0 + r];
    if (tok < 0) tok = 0;
    a_src[j] = X + (size_t)tok * DIMK + swz_col8;
  }
  const char* b_base = (const char*)Wb + ((size_t)e * DIMK * DIMK + (size_t)n0 * DIMK) * 2;

  f32x4 acc[4][2];
  const f32x4 fzero = {0.f, 0.f, 0.f, 0.f};
#pragma unroll
  for (int m = 0; m < 4; m++)
#pragma unroll
    for (int n = 0; n < 2; n++) acc[m][n] = fzero;

  const int rsel = lane & 15;
  const int swz_r = (lane & 7) << 4;
  const int kgrp = (lane >> 4) << 4;

  int a_row_b[4], b_row_b[2];
#pragma unroll
  for (int m = 0; m < 4; m++) a_row_b[m] = (wr * 64 + m * 16 + rsel) * (BK * 2);
#pragma unroll
  for (int n = 0; n < 2; n++) b_row_b[n] = (wc * 32 + n * 16 + rsel) * (BK * 2);

  for (int kt = 0; kt < NTK; kt++) {
    const int k0b = kt * (BK * 2);     // byte k-offset (bf16, for B)
    const int k0f = kt * BK;           // fp32 elem k-offset (for A)
    // B: 8 chunks via gload_lds (async into LDS)
#pragma unroll
    for (int j = 0; j < 2; j++) {
      int c = wid * 2 + j;
      int r = c * 8 + st_r;
      gload_lds16(b_base + (size_t)r * (DIMK * 2) + k0b + st_cb, (char*)B_lds + c * 1024);
    }
    // A: 4 chunks reg-staged from fp32 X, convert, ds_write (linear dest)
    us8 aw[4];
#pragma unroll
    for (int j = 0; j < 4; j++) {
      const float* p = a_src[j] + k0f;
      f32x4 v0 = *(const f32x4*)p;
      f32x4 v1 = *(const f32x4*)(p + 4);
      aw[j][0] = f2bf(v0[0]); aw[j][1] = f2bf(v0[1]);
      aw[j][2] = f2bf(v0[2]); aw[j][3] = f2bf(v0[3]);
      aw[j][4] = f2bf(v1[0]); aw[j][5] = f2bf(v1[1]);
      aw[j][6] = f2bf(v1[2]); aw[j][7] = f2bf(v1[3]);
    }
#pragma unroll
    for (int j = 0; j < 4; j++)
      *(us8*)((char*)A_lds + (wid * 4 + j) * 1024 + lane * 16) = aw[j];
    __syncthreads();   // drains B vmcnt + A ds_write lgkm for the whole block
#pragma unroll
    for (int ks = 0; ks < 2; ks++) {
      const int kb = ks * 64 + kgrp;
      short8 av[4], bv[2];
#pragma unroll
      for (int m = 0; m < 4; m++)
        av[m] = *(const short8*)((const char*)A_lds + a_row_b[m] + (kb ^ swz_r));
#pragma unroll
      for (int n = 0; n < 2; n++)
        bv[n] = *(const short8*)((const char*)B_lds + b_row_b[n] + (kb ^ swz_r));
#pragma unroll
      for (int m = 0; m < 4; m++)
#pragma unroll
        for (int n = 0; n < 2; n++)
          acc[m][n] = __builtin_amdgcn_mfma_f32_16x16x32_bf16(av[m], bv[n], acc[m][n], 0, 0, 0);
    }
    __syncthreads();   // all reads done before next kt's staging overwrites
  }

  // epilogue: scatter rows back to tokens; pad rows have row2tok == -1
  const int rg4 = (lane >> 4) * 4;
#pragma unroll
  for (int m = 0; m < 4; m++) {
#pragma unroll
    for (int i = 0; i < 4; i++) {
      int rg = row0 + wr * 64 + m * 16 + rg4 + i;
      int tok = row2tok[rg];
      if (tok >= 0) {
        float* po = out + (size_t)tok * DIMK + n0 + wc * 32 + rsel;
#pragma unroll
        for (int n = 0; n < 2; n++) po[n * 16] = acc[m][n][i];
      }
    }
  }
}

extern "C" void kernel_launch(void* const* d_in, const int* in_sizes, int n_in,
                              void* d_out, int out_size, void* d_ws, size_t ws_size,
                              hipStream_t stream) {
  const float* X = (const float*)d_in[0];
  const float* W = (const float*)d_in[1];
  const int* idx = (const int*)d_in[2];
  float* out = (float*)d_out;
  char* ws = (char*)d_ws;

  int* hdr = (int*)ws;                                     // 64 ints
  int* row2tok = (int*)(ws + 256);                         // 9216 ints
  unsigned short* Wb = (unsigned short*)(ws + 65536);      // 16 MiB bf16 W

  k_prep_conv<<<4097, 256, 0, stream>>>(idx, W, hdr, row2tok, Wb);
  k_gemm<<<NWG, 256, 0, stream>>>(X, Wb, hdr, row2tok, out);
}

// Round 11
// 68.140 us; speedup vs baseline: 1.0735x; 1.0735x over previous
//
#include <hip/hip_runtime.h>
#include <stdint.h>

#define T_TOK 8192
#define DIMK 1024
#define NEXP 8
#define BM 128
#define BN 64
#define BK 64
#define NTK (DIMK / BK)               /* 16 K-steps */
#define MAXROWS (T_TOK + NEXP * BM)   /* 9216 gathered rows incl. padding */
#define MAXTILES (T_TOK / BM + NEXP)  /* 72 row tiles worst case */
#define NT (DIMK / BN)                /* 16 n tiles */
#define NWG (MAXTILES * NT)           /* 1152 blocks, 1152 % 8 == 0 */

typedef __attribute__((ext_vector_type(4))) float f32x4;
typedef __attribute__((ext_vector_type(8))) short short8;
typedef __attribute__((ext_vector_type(8))) unsigned short us8;

__device__ __forceinline__ unsigned short f2bf(float f) {
  uint32_t u = __builtin_bit_cast(uint32_t, f);
  u += 0x7FFFu + ((u >> 16) & 1u);   // RTNE
  return (unsigned short)(u >> 16);
}

__device__ __forceinline__ void gload_lds16(const void* g, void* l) {
  __builtin_amdgcn_global_load_lds(
      (const __attribute__((address_space(1))) void*)g,
      (__attribute__((address_space(3))) void*)l, 16, 0, 0);
}

// ---- fused: prep (block 0) || W fp32->bf16 || X fp32->bf16 -----------------
__global__ void k_prep_conv(const int* __restrict__ idx, const float* __restrict__ W,
                            const float* __restrict__ X, int* __restrict__ hdr,
                            int* __restrict__ row2tok, unsigned short* __restrict__ Wb,
                            unsigned short* __restrict__ Xb) {
  const int tid = threadIdx.x;
  const int b = blockIdx.x;
  if (b == 0) {
    __shared__ int h[NEXP];
    __shared__ int cur[NEXP];
    __shared__ int segs[NEXP + 1];
    if (tid < NEXP) h[tid] = 0;
    __syncthreads();
    for (int i = tid; i < T_TOK; i += 256) atomicAdd(&h[idx[i]], 1);
    __syncthreads();
    if (tid == 0) {
      int off = 0;
      for (int e = 0; e < NEXP; e++) {
        segs[e] = off; cur[e] = off;
        hdr[e] = h[e]; hdr[8 + e] = off;
        off += ((h[e] + BM - 1) >> 7) << 7;
      }
      segs[NEXP] = off;
    }
    __syncthreads();
    for (int e = 0; e < NEXP; e++)
      for (int p = segs[e] + h[e] + tid; p < segs[e + 1]; p += 256) row2tok[p] = -1;
    for (int p = segs[NEXP] + tid; p < MAXROWS; p += 256) row2tok[p] = -1;
    for (int i = tid; i < T_TOK; i += 256) {
      int e = idx[i];
      int pos = atomicAdd(&cur[e], 1);
      row2tok[pos] = i;
    }
    return;
  }
  const float* src;
  unsigned short* dst;
  if (b <= 4096) {                    // W: 4096 blocks x 2048 elems
    size_t base = (size_t)(b - 1) * 2048 + tid * 8;
    src = W + base; dst = Wb + base;
  } else {                            // X: 4096 blocks x 2048 elems, token order
    size_t base = (size_t)(b - 4097) * 2048 + tid * 8;
    src = X + base; dst = Xb + base;
  }
  f32x4 v0 = *(const f32x4*)src;
  f32x4 v1 = *(const f32x4*)(src + 4);
  us8 o;
  o[0] = f2bf(v0[0]); o[1] = f2bf(v0[1]); o[2] = f2bf(v0[2]); o[3] = f2bf(v0[3]);
  o[4] = f2bf(v1[0]); o[5] = f2bf(v1[1]); o[6] = f2bf(v1[2]); o[7] = f2bf(v1[3]);
  *(us8*)dst = o;
}

// ---- grouped GEMM with fused A-gather: C[row] = Xb[row2tok[row]] . Wb[e]^T --
// R7 structure with "reads-to-regs-first" K-step: all 12 fragment ds_reads at
// the top, barrier frees LDS, STAGE(kt+1) issues under the 16 MFMAs (regs
// only), closing barrier drains vmcnt. Hides ds_read+MFMA time under loads.
__global__ __launch_bounds__(256, 4) void k_gemm(
    const unsigned short* __restrict__ Xb, const unsigned short* __restrict__ Wb,
    const int* __restrict__ hdr, const int* __restrict__ row2tok,
    float* __restrict__ out) {
  __shared__ unsigned short A_lds[BM * BK];  // 16 KB
  __shared__ unsigned short B_lds[BN * BK];  // 8 KB

  // XCD chunk remap: NWG=1152 % 8 == 0 -> wgid = xcd*144 + orig/8.
  const int orig = blockIdx.x;
  const int wgid = (orig & 7) * (NWG / 8) + (orig >> 3);
  int tile = wgid >> 4;               // row tile
  const int n0 = (wgid & 15) * BN;    // output column base

  // map row tile -> (expert, gathered row0) over padded segments
  int e = -1, row0 = 0;
  for (int i = 0; i < NEXP; i++) {
    int te = (hdr[i] + BM - 1) >> 7;
    if (e < 0) {
      if (tile < te) { e = i; row0 = hdr[8 + i] + tile * BM; }
      else tile -= te;
    }
  }
  if (e < 0) return;

  const int tid = threadIdx.x;
  const int lane = tid & 63;
  const int wid = tid >> 6;
  const int wr = wid >> 1, wc = wid & 1;   // wave tile 64x32

  // staging: lane covers 16B at LDS linear (chunk*1024 + lane*16).
  // LDS row = chunk*8 + (lane>>3); read side XORs col by (row&7)<<4, so the
  // *source* column carries the same XOR (both-sides-or-neither).
  const int st_r = lane >> 3;
  const int st_cb = ((lane & 7) ^ st_r) << 4;

  // resolve this lane's 4 A-row tokens ONCE (rows fixed across K-steps).
  // pad rows (tok=-1) clamp to row 0: garbage values, outputs never stored.
  const char* a_lane_base[4];
#pragma unroll
  for (int j = 0; j < 4; j++) {
    int r = (wid * 4 + j) * 8 + st_r;
    int tok = row2tok[row0 + r];
    if (tok < 0) tok = 0;
    a_lane_base[j] = (const char*)Xb + (size_t)tok * (DIMK * 2) + st_cb;
  }
  const char* b_base = (const char*)Wb + ((size_t)e * DIMK * DIMK + (size_t)n0 * DIMK) * 2;

  f32x4 acc[4][2];
  const f32x4 fzero = {0.f, 0.f, 0.f, 0.f};
#pragma unroll
  for (int m = 0; m < 4; m++)
#pragma unroll
    for (int n = 0; n < 2; n++) acc[m][n] = fzero;

  const int rsel = lane & 15;
  const int swz_r = (lane & 7) << 4;
  const int kgrp = (lane >> 4) << 4;

  int a_row_b[4], b_row_b[2];
#pragma unroll
  for (int m = 0; m < 4; m++) a_row_b[m] = (wr * 64 + m * 16 + rsel) * (BK * 2);
#pragma unroll
  for (int n = 0; n < 2; n++) b_row_b[n] = (wc * 32 + n * 16 + rsel) * (BK * 2);

#define STAGE(kt)                                                              \
  {                                                                            \
    const int k0b = (kt) * (BK * 2);                                           \
    _Pragma("unroll") for (int j = 0; j < 4; j++) {                            \
      int c = wid * 4 + j;                                                     \
      gload_lds16(a_lane_base[j] + k0b, (char*)A_lds + c * 1024);              \
    }                                                                          \
    _Pragma("unroll") for (int j = 0; j < 2; j++) {                            \
      int c = wid * 2 + j;                                                     \
      int r = c * 8 + st_r;                                                    \
      gload_lds16(b_base + (size_t)r * (DIMK * 2) + k0b + st_cb,               \
                  (char*)B_lds + c * 1024);                                    \
    }                                                                          \
  }

  STAGE(0);
  __syncthreads();   // tile 0 resident

#pragma unroll 1
  for (int kt = 0; kt < NTK; kt++) {
    // 1) all fragments -> regs (12 x ds_read_b128)
    short8 av[2][4], bv[2][2];
#pragma unroll
    for (int ks = 0; ks < 2; ks++) {
      const int kb = ks * 64 + kgrp;
#pragma unroll
      for (int m = 0; m < 4; m++)
        av[ks][m] = *(const short8*)((const char*)A_lds + a_row_b[m] + (kb ^ swz_r));
#pragma unroll
      for (int n = 0; n < 2; n++)
        bv[ks][n] = *(const short8*)((const char*)B_lds + b_row_b[n] + (kb ^ swz_r));
    }
    // 2) barrier: every wave's reads complete (lgkmcnt(0) in syncthreads),
    //    LDS is free to overwrite
    __syncthreads();
    // 3) issue next tile's async loads into the freed buffer
    if (kt + 1 < NTK) STAGE(kt + 1);
    __builtin_amdgcn_sched_barrier(0);   // keep MFMAs below the STAGE issues
    // 4) MFMAs on registers while loads fly
#pragma unroll
    for (int ks = 0; ks < 2; ks++)
#pragma unroll
      for (int m = 0; m < 4; m++)
#pragma unroll
        for (int n = 0; n < 2; n++)
          acc[m][n] = __builtin_amdgcn_mfma_f32_16x16x32_bf16(
              av[ks][m], bv[ks][n], acc[m][n], 0, 0, 0);
    // 5) drain vmcnt(0): next tile resident for the whole block
    __syncthreads();
  }
#undef STAGE

  // epilogue: scatter rows back to tokens; pad rows have row2tok == -1
  const int rg4 = (lane >> 4) * 4;
#pragma unroll
  for (int m = 0; m < 4; m++) {
#pragma unroll
    for (int i = 0; i < 4; i++) {
      int rg = row0 + wr * 64 + m * 16 + rg4 + i;
      int tok = row2tok[rg];
      if (tok >= 0) {
        float* po = out + (size_t)tok * DIMK + n0 + wc * 32 + rsel;
#pragma unroll
        for (int n = 0; n < 2; n++) po[n * 16] = acc[m][n][i];
      }
    }
  }
}

extern "C" void kernel_launch(void* const* d_in, const int* in_sizes, int n_in,
                              void* d_out, int out_size, void* d_ws, size_t ws_size,
                              hipStream_t stream) {
  const float* X = (const float*)d_in[0];
  const float* W = (const float*)d_in[1];
  const int* idx = (const int*)d_in[2];
  float* out = (float*)d_out;
  char* ws = (char*)d_ws;

  int* hdr = (int*)ws;                                     // 64 ints
  int* row2tok = (int*)(ws + 256);                         // 9216 ints
  unsigned short* Wb = (unsigned short*)(ws + 65536);      // 16 MiB bf16 W
  unsigned short* Xb = (unsigned short*)(ws + 65536 + 16777216);  // 16 MiB bf16 X (token order)

  k_prep_conv<<<8193, 256, 0, stream>>>(idx, W, X, hdr, row2tok, Wb, Xb);
  k_gemm<<<NWG, 256, 0, stream>>>(Xb, Wb, hdr, row2tok, out);
}

// Round 12
// 66.553 us; speedup vs baseline: 1.0991x; 1.0238x over previous
//
#include <hip/hip_runtime.h>
#include <stdint.h>

#define T_TOK 8192
#define DIMK 1024
#define NEXP 8
#define BM 64
#define BN 64
#define BK 64
#define NTK (DIMK / BK)               /* 16 K-steps */
#define MAXROWS (T_TOK + NEXP * BM)   /* 8704 gathered rows incl. padding */
#define MAXTILES (T_TOK / BM + NEXP)  /* 136 row tiles worst case */
#define NT (DIMK / BN)                /* 16 n tiles */
#define NWG (MAXTILES * NT)           /* 2176 blocks, 2176 % 8 == 0 */

typedef __attribute__((ext_vector_type(4))) float f32x4;
typedef __attribute__((ext_vector_type(8))) short short8;
typedef __attribute__((ext_vector_type(8))) unsigned short us8;

__device__ __forceinline__ unsigned short f2bf(float f) {
  uint32_t u = __builtin_bit_cast(uint32_t, f);
  u += 0x7FFFu + ((u >> 16) & 1u);   // RTNE
  return (unsigned short)(u >> 16);
}

__device__ __forceinline__ void gload_lds16(const void* g, void* l) {
  __builtin_amdgcn_global_load_lds(
      (const __attribute__((address_space(1))) void*)g,
      (__attribute__((address_space(3))) void*)l, 16, 0, 0);
}

// ---- fused: prep (block 0) || W fp32->bf16 || X fp32->bf16 -----------------
__global__ void k_prep_conv(const int* __restrict__ idx, const float* __restrict__ W,
                            const float* __restrict__ X, int* __restrict__ hdr,
                            int* __restrict__ row2tok, unsigned short* __restrict__ Wb,
                            unsigned short* __restrict__ Xb) {
  const int tid = threadIdx.x;
  const int b = blockIdx.x;
  if (b == 0) {
    __shared__ int h[NEXP];
    __shared__ int cur[NEXP];
    __shared__ int segs[NEXP + 1];
    if (tid < NEXP) h[tid] = 0;
    __syncthreads();
    for (int i = tid; i < T_TOK; i += 256) atomicAdd(&h[idx[i]], 1);
    __syncthreads();
    if (tid == 0) {
      int off = 0;
      for (int e = 0; e < NEXP; e++) {
        segs[e] = off; cur[e] = off;
        hdr[e] = h[e]; hdr[8 + e] = off;
        off += ((h[e] + BM - 1) / BM) * BM;   // pad to 64-row multiples
      }
      segs[NEXP] = off;
    }
    __syncthreads();
    for (int e = 0; e < NEXP; e++)
      for (int p = segs[e] + h[e] + tid; p < segs[e + 1]; p += 256) row2tok[p] = -1;
    for (int p = segs[NEXP] + tid; p < MAXROWS; p += 256) row2tok[p] = -1;
    for (int i = tid; i < T_TOK; i += 256) {
      int e = idx[i];
      int pos = atomicAdd(&cur[e], 1);
      row2tok[pos] = i;
    }
    return;
  }
  const float* src;
  unsigned short* dst;
  if (b <= 4096) {                    // W: 4096 blocks x 2048 elems
    size_t base = (size_t)(b - 1) * 2048 + tid * 8;
    src = W + base; dst = Wb + base;
  } else {                            // X: 4096 blocks x 2048 elems, token order
    size_t base = (size_t)(b - 4097) * 2048 + tid * 8;
    src = X + base; dst = Xb + base;
  }
  f32x4 v0 = *(const f32x4*)src;
  f32x4 v1 = *(const f32x4*)(src + 4);
  us8 o;
  o[0] = f2bf(v0[0]); o[1] = f2bf(v0[1]); o[2] = f2bf(v0[2]); o[3] = f2bf(v0[3]);
  o[4] = f2bf(v1[0]); o[5] = f2bf(v1[1]); o[6] = f2bf(v1[2]); o[7] = f2bf(v1[3]);
  *(us8*)dst = o;
}

// ---- grouped GEMM with fused A-gather: C[row] = Xb[row2tok[row]] . Wb[e]^T --
// 64x64 tiles: grid 2176 (8.5 blocks/CU), LDS 16 KB -> wave-cap 8 blocks/CU
// resident in ONE round. Streams/CU is the only lever that has ever paid
// (R4->R5); this doubles it. Proven single-buffer 2-barrier K-loop unchanged.
__global__ __launch_bounds__(256, 8) void k_gemm(
    const unsigned short* __restrict__ Xb, const unsigned short* __restrict__ Wb,
    const int* __restrict__ hdr, const int* __restrict__ row2tok,
    float* __restrict__ out) {
  __shared__ unsigned short A_lds[BM * BK];  // 8 KB
  __shared__ unsigned short B_lds[BN * BK];  // 8 KB

  // XCD chunk remap: NWG=2176 % 8 == 0 -> wgid = xcd*272 + orig/8.
  const int orig = blockIdx.x;
  const int wgid = (orig & 7) * (NWG / 8) + (orig >> 3);
  int tile = wgid >> 4;               // row tile
  const int n0 = (wgid & 15) * BN;    // output column base

  // map row tile -> (expert, gathered row0) over padded segments
  int e = -1, row0 = 0;
  for (int i = 0; i < NEXP; i++) {
    int te = (hdr[i] + BM - 1) / BM;
    if (e < 0) {
      if (tile < te) { e = i; row0 = hdr[8 + i] + tile * BM; }
      else tile -= te;
    }
  }
  if (e < 0) return;

  const int tid = threadIdx.x;
  const int lane = tid & 63;
  const int wid = tid >> 6;
  const int wr = wid >> 1, wc = wid & 1;   // wave tile 32x32

  // staging: lane covers 16B at LDS linear (chunk*1024 + lane*16).
  // LDS row = chunk*8 + (lane>>3); read side XORs col by (row&7)<<4, so the
  // *source* column carries the same XOR (both-sides-or-neither).
  const int st_r = lane >> 3;
  const int st_cb = ((lane & 7) ^ st_r) << 4;

  // resolve this lane's 2 A-row tokens ONCE (rows fixed across K-steps).
  // pad rows (tok=-1) clamp to row 0: garbage values, outputs never stored.
  const char* a_lane_base[2];
#pragma unroll
  for (int j = 0; j < 2; j++) {
    int r = (wid * 2 + j) * 8 + st_r;
    int tok = row2tok[row0 + r];
    if (tok < 0) tok = 0;
    a_lane_base[j] = (const char*)Xb + (size_t)tok * (DIMK * 2) + st_cb;
  }
  const char* b_base = (const char*)Wb + ((size_t)e * DIMK * DIMK + (size_t)n0 * DIMK) * 2;

  f32x4 acc[2][2];
  const f32x4 fzero = {0.f, 0.f, 0.f, 0.f};
#pragma unroll
  for (int m = 0; m < 2; m++)
#pragma unroll
    for (int n = 0; n < 2; n++) acc[m][n] = fzero;

  const int rsel = lane & 15;
  const int swz_r = (lane & 7) << 4;
  const int kgrp = (lane >> 4) << 4;

  int a_row_b[2], b_row_b[2];
#pragma unroll
  for (int m = 0; m < 2; m++) a_row_b[m] = (wr * 32 + m * 16 + rsel) * (BK * 2);
#pragma unroll
  for (int n = 0; n < 2; n++) b_row_b[n] = (wc * 32 + n * 16 + rsel) * (BK * 2);

  for (int kt = 0; kt < NTK; kt++) {
    const int k0b = kt * (BK * 2);
    // stage A (8 chunks) + B (8 chunks); 4 gload_lds per wave
#pragma unroll
    for (int j = 0; j < 2; j++) {
      int c = wid * 2 + j;
      int r = c * 8 + st_r;
      gload_lds16(a_lane_base[j] + k0b, (char*)A_lds + c * 1024);
      gload_lds16(b_base + (size_t)r * (DIMK * 2) + k0b + st_cb, (char*)B_lds + c * 1024);
    }
    __syncthreads();
#pragma unroll
    for (int ks = 0; ks < 2; ks++) {
      const int kb = ks * 64 + kgrp;
      short8 av[2], bv[2];
#pragma unroll
      for (int m = 0; m < 2; m++)
        av[m] = *(const short8*)((const char*)A_lds + a_row_b[m] + (kb ^ swz_r));
#pragma unroll
      for (int n = 0; n < 2; n++)
        bv[n] = *(const short8*)((const char*)B_lds + b_row_b[n] + (kb ^ swz_r));
#pragma unroll
      for (int m = 0; m < 2; m++)
#pragma unroll
        for (int n = 0; n < 2; n++)
          acc[m][n] = __builtin_amdgcn_mfma_f32_16x16x32_bf16(av[m], bv[n], acc[m][n], 0, 0, 0);
    }
    __syncthreads();
  }

  // epilogue: scatter rows back to tokens; pad rows have row2tok == -1
  const int rg4 = (lane >> 4) * 4;
#pragma unroll
  for (int m = 0; m < 2; m++) {
#pragma unroll
    for (int i = 0; i < 4; i++) {
      int rg = row0 + wr * 32 + m * 16 + rg4 + i;
      int tok = row2tok[rg];
      if (tok >= 0) {
        float* po = out + (size_t)tok * DIMK + n0 + wc * 32 + rsel;
#pragma unroll
        for (int n = 0; n < 2; n++) po[n * 16] = acc[m][n][i];
      }
    }
  }
}

extern "C" void kernel_launch(void* const* d_in, const int* in_sizes, int n_in,
                              void* d_out, int out_size, void* d_ws, size_t ws_size,
                              hipStream_t stream) {
  const float* X = (const float*)d_in[0];
  const float* W = (const float*)d_in[1];
  const int* idx = (const int*)d_in[2];
  float* out = (float*)d_out;
  char* ws = (char*)d_ws;

  int* hdr = (int*)ws;                                     // 64 ints
  int* row2tok = (int*)(ws + 256);                         // 8704 ints
  unsigned short* Wb = (unsigned short*)(ws + 65536);      // 16 MiB bf16 W
  unsigned short* Xb = (unsigned short*)(ws + 65536 + 16777216);  // 16 MiB bf16 X (token order)

  k_prep_conv<<<8193, 256, 0, stream>>>(idx, W, X, hdr, row2tok, Wb, Xb);
  k_gemm<<<NWG, 256, 0, stream>>>(Xb, Wb, hdr, row2tok, out);
}

// Round 13
// 60.607 us; speedup vs baseline: 1.2069x; 1.0981x over previous
//
#include <hip/hip_runtime.h>
#include <stdint.h>

#define T_TOK 8192
#define DIMK 1024
#define NEXP 8
#define BM 128
#define BN 128
#define BK 64
#define NTK (DIMK / BK)               /* 16 K-steps */
#define MAXROWS (T_TOK + NEXP * BM)   /* 9216 gathered rows incl. padding */
#define MAXTILES (T_TOK / BM + NEXP)  /* 72 row tiles worst case */
#define NT (DIMK / BN)                /* 8 n tiles */
#define NWG (MAXTILES * NT)           /* 576 blocks, 576 % 8 == 0 */

typedef __attribute__((ext_vector_type(4))) float f32x4;
typedef __attribute__((ext_vector_type(8))) short short8;
typedef __attribute__((ext_vector_type(8))) unsigned short us8;

__device__ __forceinline__ unsigned short f2bf(float f) {
  uint32_t u = __builtin_bit_cast(uint32_t, f);
  u += 0x7FFFu + ((u >> 16) & 1u);   // RTNE
  return (unsigned short)(u >> 16);
}

__device__ __forceinline__ void gload_lds16(const void* g, void* l) {
  __builtin_amdgcn_global_load_lds(
      (const __attribute__((address_space(1))) void*)g,
      (__attribute__((address_space(3))) void*)l, 16, 0, 0);
}

// ---- fused: prep (block 0) || W fp32->bf16 || X fp32->bf16 -----------------
__global__ void k_prep_conv(const int* __restrict__ idx, const float* __restrict__ W,
                            const float* __restrict__ X, int* __restrict__ hdr,
                            int* __restrict__ row2tok, unsigned short* __restrict__ Wb,
                            unsigned short* __restrict__ Xb) {
  const int tid = threadIdx.x;
  const int b = blockIdx.x;
  if (b == 0) {
    __shared__ int h[NEXP];
    __shared__ int cur[NEXP];
    __shared__ int segs[NEXP + 1];
    if (tid < NEXP) h[tid] = 0;
    __syncthreads();
    for (int i = tid; i < T_TOK; i += 256) atomicAdd(&h[idx[i]], 1);
    __syncthreads();
    if (tid == 0) {
      int off = 0;
      for (int e = 0; e < NEXP; e++) {
        segs[e] = off; cur[e] = off;
        hdr[e] = h[e]; hdr[8 + e] = off;
        off += ((h[e] + BM - 1) >> 7) << 7;   // pad to 128-row multiples
      }
      segs[NEXP] = off;
    }
    __syncthreads();
    for (int e = 0; e < NEXP; e++)
      for (int p = segs[e] + h[e] + tid; p < segs[e + 1]; p += 256) row2tok[p] = -1;
    for (int p = segs[NEXP] + tid; p < MAXROWS; p += 256) row2tok[p] = -1;
    for (int i = tid; i < T_TOK; i += 256) {
      int e = idx[i];
      int pos = atomicAdd(&cur[e], 1);
      row2tok[pos] = i;
    }
    return;
  }
  const float* src;
  unsigned short* dst;
  if (b <= 4096) {                    // W: 4096 blocks x 2048 elems
    size_t base = (size_t)(b - 1) * 2048 + tid * 8;
    src = W + base; dst = Wb + base;
  } else {                            // X: 4096 blocks x 2048 elems, token order
    size_t base = (size_t)(b - 4097) * 2048 + tid * 8;
    src = X + base; dst = Xb + base;
  }
  f32x4 v0 = *(const f32x4*)src;
  f32x4 v1 = *(const f32x4*)(src + 4);
  us8 o;
  o[0] = f2bf(v0[0]); o[1] = f2bf(v0[1]); o[2] = f2bf(v0[2]); o[3] = f2bf(v0[3]);
  o[4] = f2bf(v1[0]); o[5] = f2bf(v1[1]); o[6] = f2bf(v1[2]); o[7] = f2bf(v1[3]);
  *(us8*)dst = o;
}

// ---- grouped GEMM with fused A-gather: C[row] = Xb[row2tok[row]] . Wb[e]^T --
// 128x128 tile / 512-thread 8-wave block: minimum cache traffic (285 MB) at
// R5-level parallelism (~18 waves/CU; grid 576 = 2.25 blocks/CU, 32 KB LDS).
// Proven single-buffer 2-barrier K-loop; per-wave mix identical to R5.
__global__ __launch_bounds__(512, 6) void k_gemm(
    const unsigned short* __restrict__ Xb, const unsigned short* __restrict__ Wb,
    const int* __restrict__ hdr, const int* __restrict__ row2tok,
    float* __restrict__ out) {
  __shared__ unsigned short A_lds[BM * BK];  // 16 KB
  __shared__ unsigned short B_lds[BN * BK];  // 16 KB

  // XCD chunk remap: NWG=576 % 8 == 0 -> wgid = xcd*72 + orig/8.
  // 72 = 9 row-tiles x 8 n-tiles per XCD chunk (A + W panels L2-local).
  const int orig = blockIdx.x;
  const int wgid = (orig & 7) * (NWG / 8) + (orig >> 3);
  int tile = wgid >> 3;               // row tile
  const int n0 = (wgid & 7) * BN;     // output column base

  // map row tile -> (expert, gathered row0) over padded segments
  int e = -1, row0 = 0;
  for (int i = 0; i < NEXP; i++) {
    int te = (hdr[i] + BM - 1) >> 7;
    if (e < 0) {
      if (tile < te) { e = i; row0 = hdr[8 + i] + tile * BM; }
      else tile -= te;
    }
  }
  if (e < 0) return;

  const int tid = threadIdx.x;
  const int lane = tid & 63;
  const int wid = tid >> 6;                 // 0..7
  const int wr = wid >> 2, wc = wid & 3;    // wave grid 2x4, wave tile 64x32

  // staging: lane covers 16B at LDS linear (chunk*1024 + lane*16).
  // LDS row = chunk*8 + (lane>>3); read side XORs col by (row&7)<<4, so the
  // *source* column carries the same XOR (both-sides-or-neither).
  const int st_r = lane >> 3;
  const int st_cb = ((lane & 7) ^ st_r) << 4;

  // resolve this lane's 2 A-row tokens ONCE (rows fixed across K-steps).
  // pad rows (tok=-1) clamp to row 0: garbage values, outputs never stored.
  const char* a_lane_base[2];
#pragma unroll
  for (int j = 0; j < 2; j++) {
    int r = (wid * 2 + j) * 8 + st_r;
    int tok = row2tok[row0 + r];
    if (tok < 0) tok = 0;
    a_lane_base[j] = (const char*)Xb + (size_t)tok * (DIMK * 2) + st_cb;
  }
  const char* b_base = (const char*)Wb + ((size_t)e * DIMK * DIMK + (size_t)n0 * DIMK) * 2;

  f32x4 acc[4][2];
  const f32x4 fzero = {0.f, 0.f, 0.f, 0.f};
#pragma unroll
  for (int m = 0; m < 4; m++)
#pragma unroll
    for (int n = 0; n < 2; n++) acc[m][n] = fzero;

  const int rsel = lane & 15;
  const int swz_r = (lane & 7) << 4;
  const int kgrp = (lane >> 4) << 4;

  int a_row_b[4], b_row_b[2];
#pragma unroll
  for (int m = 0; m < 4; m++) a_row_b[m] = (wr * 64 + m * 16 + rsel) * (BK * 2);
#pragma unroll
  for (int n = 0; n < 2; n++) b_row_b[n] = (wc * 32 + n * 16 + rsel) * (BK * 2);

  for (int kt = 0; kt < NTK; kt++) {
    const int k0b = kt * (BK * 2);
    // stage A (16 chunks) + B (16 chunks); 4 gload_lds per wave
#pragma unroll
    for (int j = 0; j < 2; j++) {
      int c = wid * 2 + j;
      int r = c * 8 + st_r;
      gload_lds16(a_lane_base[j] + k0b, (char*)A_lds + c * 1024);
      gload_lds16(b_base + (size_t)r * (DIMK * 2) + k0b + st_cb, (char*)B_lds + c * 1024);
    }
    __syncthreads();
#pragma unroll
    for (int ks = 0; ks < 2; ks++) {
      const int kb = ks * 64 + kgrp;
      short8 av[4], bv[2];
#pragma unroll
      for (int m = 0; m < 4; m++)
        av[m] = *(const short8*)((const char*)A_lds + a_row_b[m] + (kb ^ swz_r));
#pragma unroll
      for (int n = 0; n < 2; n++)
        bv[n] = *(const short8*)((const char*)B_lds + b_row_b[n] + (kb ^ swz_r));
#pragma unroll
      for (int m = 0; m < 4; m++)
#pragma unroll
        for (int n = 0; n < 2; n++)
          acc[m][n] = __builtin_amdgcn_mfma_f32_16x16x32_bf16(av[m], bv[n], acc[m][n], 0, 0, 0);
    }
    __syncthreads();
  }

  // epilogue: scatter rows back to tokens; pad rows have row2tok == -1
  const int rg4 = (lane >> 4) * 4;
#pragma unroll
  for (int m = 0; m < 4; m++) {
#pragma unroll
    for (int i = 0; i < 4; i++) {
      int rg = row0 + wr * 64 + m * 16 + rg4 + i;
      int tok = row2tok[rg];
      if (tok >= 0) {
        float* po = out + (size_t)tok * DIMK + n0 + wc * 32 + rsel;
#pragma unroll
        for (int n = 0; n < 2; n++) po[n * 16] = acc[m][n][i];
      }
    }
  }
}

extern "C" void kernel_launch(void* const* d_in, const int* in_sizes, int n_in,
                              void* d_out, int out_size, void* d_ws, size_t ws_size,
                              hipStream_t stream) {
  const float* X = (const float*)d_in[0];
  const float* W = (const float*)d_in[1];
  const int* idx = (const int*)d_in[2];
  float* out = (float*)d_out;
  char* ws = (char*)d_ws;

  int* hdr = (int*)ws;                                     // 64 ints
  int* row2tok = (int*)(ws + 256);                         // 9216 ints
  unsigned short* Wb = (unsigned short*)(ws + 65536);      // 16 MiB bf16 W
  unsigned short* Xb = (unsigned short*)(ws + 65536 + 16777216);  // 16 MiB bf16 X (token order)

  k_prep_conv<<<8193, 256, 0, stream>>>(idx, W, X, hdr, row2tok, Wb, Xb);
  k_gemm<<<NWG, 512, 0, stream>>>(Xb, Wb, hdr, row2tok, out);
}

// Round 14
// 59.734 us; speedup vs baseline: 1.2246x; 1.0146x over previous
//
#include <hip/hip_runtime.h>
#include <stdint.h>

#define T_TOK 8192
#define DIMK 1024
#define NEXP 8
#define BM 128
#define BN 128
#define BK 64
#define NTK (DIMK / BK)               /* 16 K-steps */
#define MAXROWS (T_TOK + NEXP * BM)   /* 9216 gathered rows incl. padding */
#define MAXTILES (T_TOK / BM + NEXP)  /* 72 row tiles worst case */
#define NT (DIMK / BN)                /* 8 n tiles */
#define NWG (MAXTILES * NT)           /* 576 blocks, 576 % 8 == 0 */

typedef __attribute__((ext_vector_type(4))) float f32x4;
typedef __attribute__((ext_vector_type(8))) short short8;
typedef __attribute__((ext_vector_type(8))) unsigned short us8;

__device__ __forceinline__ unsigned short f2bf(float f) {
  uint32_t u = __builtin_bit_cast(uint32_t, f);
  u += 0x7FFFu + ((u >> 16) & 1u);   // RTNE
  return (unsigned short)(u >> 16);
}

__device__ __forceinline__ void gload_lds16(const void* g, void* l) {
  __builtin_amdgcn_global_load_lds(
      (const __attribute__((address_space(1))) void*)g,
      (__attribute__((address_space(3))) void*)l, 16, 0, 0);
}

// ---- fused: prep (block 0) || W fp32->bf16 || X fp32->bf16 -----------------
__global__ void k_prep_conv(const int* __restrict__ idx, const float* __restrict__ W,
                            const float* __restrict__ X, int* __restrict__ hdr,
                            int* __restrict__ row2tok, unsigned short* __restrict__ Wb,
                            unsigned short* __restrict__ Xb) {
  const int tid = threadIdx.x;
  const int b = blockIdx.x;
  if (b == 0) {
    __shared__ int h[NEXP];
    __shared__ int cur[NEXP];
    __shared__ int segs[NEXP + 1];
    if (tid < NEXP) h[tid] = 0;
    __syncthreads();
    for (int i = tid; i < T_TOK; i += 256) atomicAdd(&h[idx[i]], 1);
    __syncthreads();
    if (tid == 0) {
      int off = 0;
      for (int e = 0; e < NEXP; e++) {
        segs[e] = off; cur[e] = off;
        hdr[e] = h[e]; hdr[8 + e] = off;
        off += ((h[e] + BM - 1) >> 7) << 7;   // pad to 128-row multiples
      }
      segs[NEXP] = off;
    }
    __syncthreads();
    for (int e = 0; e < NEXP; e++)
      for (int p = segs[e] + h[e] + tid; p < segs[e + 1]; p += 256) row2tok[p] = -1;
    for (int p = segs[NEXP] + tid; p < MAXROWS; p += 256) row2tok[p] = -1;
    for (int i = tid; i < T_TOK; i += 256) {
      int e = idx[i];
      int pos = atomicAdd(&cur[e], 1);
      row2tok[pos] = i;
    }
    return;
  }
  const float* src;
  unsigned short* dst;
  if (b <= 4096) {                    // W: 4096 blocks x 2048 elems
    size_t base = (size_t)(b - 1) * 2048 + tid * 8;
    src = W + base; dst = Wb + base;
  } else {                            // X: 4096 blocks x 2048 elems, token order
    size_t base = (size_t)(b - 4097) * 2048 + tid * 8;
    src = X + base; dst = Xb + base;
  }
  f32x4 v0 = *(const f32x4*)src;
  f32x4 v1 = *(const f32x4*)(src + 4);
  us8 o;
  o[0] = f2bf(v0[0]); o[1] = f2bf(v0[1]); o[2] = f2bf(v0[2]); o[3] = f2bf(v0[3]);
  o[4] = f2bf(v1[0]); o[5] = f2bf(v1[1]); o[6] = f2bf(v1[2]); o[7] = f2bf(v1[3]);
  *(us8*)dst = o;
}

// ---- grouped GEMM with fused A-gather: C[row] = Xb[row2tok[row]] . Wb[e]^T --
// R13 structure (128x128 tile, 512-thread 8-wave block, single-buffer
// 2-barrier K-loop) + EXPERT-AFFINE XCD MAPPING: XCD x computes expert x, so
// the per-XCD concurrent working set is W_x (2MB) + its A rows (~2.25MB),
// fitting the 4MB XCD L2 (before: ~2 experts' W + A = 6+MB -> L2 thrash ->
// L3-BW-bound ~13 TB/s). Overflow tiles (T_e>9) handled via leftover slots —
// correct for ANY index distribution (sum of tiles <= 71 < 72 slots/XCD).
__global__ __launch_bounds__(512, 6) void k_gemm(
    const unsigned short* __restrict__ Xb, const unsigned short* __restrict__ Wb,
    const int* __restrict__ hdr, const int* __restrict__ row2tok,
    float* __restrict__ out) {
  __shared__ unsigned short A_lds[BM * BK];  // 16 KB
  __shared__ unsigned short B_lds[BN * BK];  // 16 KB

  // per-expert tile counts
  int T[NEXP];
#pragma unroll
  for (int i = 0; i < NEXP; i++) T[i] = (hdr[i] + BM - 1) >> 7;

  const int orig = blockIdx.x;
  const int xcd = orig & 7;           // HW: consecutive blocks round-robin XCDs
  const int slot = orig >> 3;         // 0..71 within this XCD
  int e = -1, tl = 0, nq = 0;
  {
    int P = T[xcd] < 9 ? T[xcd] : 9;  // primary tiles on home XCD
    if (slot < 8 * P) {
      e = xcd; tl = slot % P; nq = slot / P;
    } else {
      // leftover slot: global rank over all XCDs' spare slots
      int r = slot - 8 * P;
      for (int i = 0; i < xcd; i++) r += 72 - 8 * (T[i] < 9 ? T[i] : 9);
      // map rank -> overflow units (experts with T>9), in expert order
      for (int i = 0; i < NEXP && e < 0; i++) {
        int ot = T[i] - 9;
        if (ot > 0) {
          if (r < 8 * ot) { e = i; tl = 9 + r % ot; nq = r / ot; }
          else r -= 8 * ot;
        }
      }
    }
  }
  if (e < 0) return;
  const int n0 = nq * BN;             // output column base
  const int row0 = hdr[8 + e] + tl * BM;

  const int tid = threadIdx.x;
  const int lane = tid & 63;
  const int wid = tid >> 6;                 // 0..7
  const int wr = wid >> 2, wc = wid & 3;    // wave grid 2x4, wave tile 64x32

  // staging: lane covers 16B at LDS linear (chunk*1024 + lane*16).
  // LDS row = chunk*8 + (lane>>3); read side XORs col by (row&7)<<4, so the
  // *source* column carries the same XOR (both-sides-or-neither).
  const int st_r = lane >> 3;
  const int st_cb = ((lane & 7) ^ st_r) << 4;

  // resolve this lane's 2 A-row tokens ONCE (rows fixed across K-steps).
  // pad rows (tok=-1) clamp to row 0: garbage values, outputs never stored.
  const char* a_lane_base[2];
#pragma unroll
  for (int j = 0; j < 2; j++) {
    int r = (wid * 2 + j) * 8 + st_r;
    int tok = row2tok[row0 + r];
    if (tok < 0) tok = 0;
    a_lane_base[j] = (const char*)Xb + (size_t)tok * (DIMK * 2) + st_cb;
  }
  const char* b_base = (const char*)Wb + ((size_t)e * DIMK * DIMK + (size_t)n0 * DIMK) * 2;

  f32x4 acc[4][2];
  const f32x4 fzero = {0.f, 0.f, 0.f, 0.f};
#pragma unroll
  for (int m = 0; m < 4; m++)
#pragma unroll
    for (int n = 0; n < 2; n++) acc[m][n] = fzero;

  const int rsel = lane & 15;
  const int swz_r = (lane & 7) << 4;
  const int kgrp = (lane >> 4) << 4;

  int a_row_b[4], b_row_b[2];
#pragma unroll
  for (int m = 0; m < 4; m++) a_row_b[m] = (wr * 64 + m * 16 + rsel) * (BK * 2);
#pragma unroll
  for (int n = 0; n < 2; n++) b_row_b[n] = (wc * 32 + n * 16 + rsel) * (BK * 2);

  for (int kt = 0; kt < NTK; kt++) {
    const int k0b = kt * (BK * 2);
    // stage A (16 chunks) + B (16 chunks); 4 gload_lds per wave
#pragma unroll
    for (int j = 0; j < 2; j++) {
      int c = wid * 2 + j;
      int r = c * 8 + st_r;
      gload_lds16(a_lane_base[j] + k0b, (char*)A_lds + c * 1024);
      gload_lds16(b_base + (size_t)r * (DIMK * 2) + k0b + st_cb, (char*)B_lds + c * 1024);
    }
    __syncthreads();
#pragma unroll
    for (int ks = 0; ks < 2; ks++) {
      const int kb = ks * 64 + kgrp;
      short8 av[4], bv[2];
#pragma unroll
      for (int m = 0; m < 4; m++)
        av[m] = *(const short8*)((const char*)A_lds + a_row_b[m] + (kb ^ swz_r));
#pragma unroll
      for (int n = 0; n < 2; n++)
        bv[n] = *(const short8*)((const char*)B_lds + b_row_b[n] + (kb ^ swz_r));
#pragma unroll
      for (int m = 0; m < 4; m++)
#pragma unroll
        for (int n = 0; n < 2; n++)
          acc[m][n] = __builtin_amdgcn_mfma_f32_16x16x32_bf16(av[m], bv[n], acc[m][n], 0, 0, 0);
    }
    __syncthreads();
  }

  // epilogue: scatter rows back to tokens; pad rows have row2tok == -1
  const int rg4 = (lane >> 4) * 4;
#pragma unroll
  for (int m = 0; m < 4; m++) {
#pragma unroll
    for (int i = 0; i < 4; i++) {
      int rg = row0 + wr * 64 + m * 16 + rg4 + i;
      int tok = row2tok[rg];
      if (tok >= 0) {
        float* po = out + (size_t)tok * DIMK + n0 + wc * 32 + rsel;
#pragma unroll
        for (int n = 0; n < 2; n++) po[n * 16] = acc[m][n][i];
      }
    }
  }
}

extern "C" void kernel_launch(void* const* d_in, const int* in_sizes, int n_in,
                              void* d_out, int out_size, void* d_ws, size_t ws_size,
                              hipStream_t stream) {
  const float* X = (const float*)d_in[0];
  const float* W = (const float*)d_in[1];
  const int* idx = (const int*)d_in[2];
  float* out = (float*)d_out;
  char* ws = (char*)d_ws;

  int* hdr = (int*)ws;                                     // 64 ints
  int* row2tok = (int*)(ws + 256);                         // 9216 ints
  unsigned short* Wb = (unsigned short*)(ws + 65536);      // 16 MiB bf16 W
  unsigned short* Xb = (unsigned short*)(ws + 65536 + 16777216);  // 16 MiB bf16 X (token order)

  k_prep_conv<<<8193, 256, 0, stream>>>(idx, W, X, hdr, row2tok, Wb, Xb);
  k_gemm<<<NWG, 512, 0, stream>>>(Xb, Wb, hdr, row2tok, out);
}